// Round 3
// baseline (185.889 us; speedup 1.0000x reference)
//
#include <hip/hip_runtime.h>

// out[b,o] = x[b,:] @ W_lin[:,o] + x[b] @ W_nl[o] @ x[b]
// Symmetric GEMM form (K=640 via 10 folded 8x8 block-pairs of W_nl+W_nl^T),
// 20 k-steps split across 4 waves (5 each), B' fragments in registers.
// This round: TWO 16-row tiles per iteration (one 32-row chunk), one barrier
// per chunk; 4 independent MFMA accumulator chains; x staged via ONE
// coalesced floatx4/thread into an XOR-swizzled unpadded LDS buffer
// (prefetched a full iteration ahead); partials exchanged through a
// b128-granule-swizzled reduce buffer (2-way max bank aliasing everywhere).
// LDS = 40960 B exactly -> 4 blocks/CU; one barrier per 32 rows.

typedef __attribute__((ext_vector_type(8))) __bf16 bf16x8;
typedef __attribute__((ext_vector_type(4))) float floatx4;

#define NB     524288
#define NCHUNK (NB / 32)       // 16384 chunks of 32 rows
#define GRID   1024
#define ITERS  (NCHUNK / GRID) // 16

// swizzled x word index: row r (0..31), element e (0..31)
__device__ __forceinline__ int XW(int r, int e) {
    return r * 32 + ((((e >> 2) ^ (r & 7)) << 2) | (e & 3));
}

__global__ __launch_bounds__(256, 4)
void nnode_kernel(const float* __restrict__ x, const float* __restrict__ Wlin,
                  const float* __restrict__ Wnl, float* __restrict__ out) {
    __shared__ __align__(16) float xs[2][1024];       // 8 KiB, swizzled 32x32
    __shared__ __align__(16) float red[2][2][2048];   // 32 KiB, [buf][tile]

    const int tid  = threadIdx.x;
    const int wave = tid >> 6;
    const int lane = tid & 63;
    const int q    = lane >> 4;   // quad: A k-window / C row group
    const int col  = lane & 15;   // output column / A row (within tile)

    // ---- step table + B' fragments (wave w owns global steps 5w..5w+5) ----
    // step t: pair p=t>>1, half h=t&1; pairs: (0,0)(0,1)(0,2)(0,3)(1,1)(1,2)
    // (1,3)(2,2)(2,3)(3,3). A k-slot (q,j) <-> (u=4h+q, v=j).
    int eoffs[5], woffs[5];
    bf16x8 bW[5][2];
    #pragma unroll
    for (int kl = 0; kl < 5; ++kl) {
        const int t  = wave * 5 + kl;
        const int p  = t >> 1, h = t & 1;
        const int pa = (p < 4) ? 0 : ((p < 7) ? 1 : ((p < 9) ? 2 : 3));
        const int pb = p - ((p < 4) ? 0 : ((p < 7) ? 3 : ((p < 9) ? 5 : 6)));
        eoffs[kl] = 8 * pa + 4 * h;   // scalar element offset (add q per lane)
        woffs[kl] = 8 * pb;           // vector window offset
        const bool diag = (pa == pb);
        const int  i1   = eoffs[kl] + q;          // = 8a + u
        #pragma unroll
        for (int tt = 0; tt < 2; ++tt) {
            const float* base = Wnl + (size_t)(col + 16 * tt) * 1024;
            floatx4 v0 = *(const floatx4*)(base + i1 * 32 + woffs[kl]);
            floatx4 v1 = *(const floatx4*)(base + i1 * 32 + woffs[kl] + 4);
            if (!diag) {   // += W_nl[o, 8b+v, 8a+u]
                #pragma unroll
                for (int j = 0; j < 4; ++j) {
                    v0[j] += base[(size_t)(woffs[kl] + j) * 32 + i1];
                    v1[j] += base[(size_t)(woffs[kl] + 4 + j) * 32 + i1];
                }
            }
            bf16x8 f;
            #pragma unroll
            for (int j = 0; j < 4; ++j) { f[j] = (__bf16)v0[j]; f[j + 4] = (__bf16)v1[j]; }
            bW[kl][tt] = f;
        }
    }

    // ---- linear-part B fragments, quarter-scaled (all 4 waves add 1/4) ----
    bf16x8 bl0, bl1;
    #pragma unroll
    for (int j = 0; j < 8; ++j) {
        bl0[j] = (__bf16)(0.25f * Wlin[(q * 8 + j) * 32 + col]);
        bl1[j] = (__bf16)(0.25f * Wlin[(q * 8 + j) * 32 + col + 16]);
    }

    // staging indices: thread -> (row tid>>3, granule tid&7), swizzled word
    const int sword = (tid >> 3) * 32 + (((tid & 7) ^ ((tid >> 3) & 7)) << 2);
    // partial-write granule position (same for col and col+16)
    const int pofs  = ((q + (col >> 1)) & 3) << 2;
    // reducer constants: thread -> (tile, col, row-quad)
    const int rt  = tid >> 7;
    const int rc  = tid & 31;
    const int rqd = (tid >> 5) & 3;
    const int rp4 = ((rqd + (rc >> 1)) & 3) << 2;

    // ---- prologue: stage chunk blockIdx.x into xs[0] ----
    {
        floatx4 v = *(const floatx4*)(x + (size_t)blockIdx.x * 1024 + tid * 4);
        *(floatx4*)&xs[0][sword] = v;
    }
    __syncthreads();

    for (int it = 0; it < ITERS; ++it) {
        const int chunk = blockIdx.x + it * GRID;
        const int cur   = it & 1;

        // prefetch next chunk (coalesced 4KB/block) early; landed after compute
        floatx4 pre;
        if (it < ITERS - 1)
            pre = *(const floatx4*)(x + (size_t)(chunk + GRID) * 1024 + tid * 4);

        const float* xb = xs[cur];
        floatx4 acc0[2] = {{0.f,0.f,0.f,0.f},{0.f,0.f,0.f,0.f}};
        floatx4 acc1[2] = {{0.f,0.f,0.f,0.f},{0.f,0.f,0.f,0.f}};

        #pragma unroll
        for (int t = 0; t < 2; ++t) {
            const int r = t * 16 + col;   // this lane's x row within chunk

            // linear tail (quarter-scaled, window at q*8)
            {
                floatx4 a0 = *(const floatx4*)(xb + XW(r, q * 8));
                floatx4 a1 = *(const floatx4*)(xb + XW(r, q * 8 + 4));
                bf16x8 af;
                #pragma unroll
                for (int j = 0; j < 4; ++j) { af[j] = (__bf16)a0[j]; af[j + 4] = (__bf16)a1[j]; }
                acc0[t] = __builtin_amdgcn_mfma_f32_16x16x32_bf16(af, bl0, acc0[t], 0, 0, 0);
                acc1[t] = __builtin_amdgcn_mfma_f32_16x16x32_bf16(af, bl1, acc1[t], 0, 0, 0);
            }

            // 5 symmetric-packed k-steps: af[j] = x[8a+4h+q] * x[8b+j]
            #pragma unroll
            for (int kl = 0; kl < 5; ++kl) {
                const float sc = xb[XW(r, eoffs[kl] + q)];
                floatx4 w0 = *(const floatx4*)(xb + XW(r, woffs[kl]));
                floatx4 w1 = *(const floatx4*)(xb + XW(r, woffs[kl] + 4));
                bf16x8 af;
                #pragma unroll
                for (int j = 0; j < 4; ++j) {
                    af[j]     = (__bf16)(sc * w0[j]);
                    af[j + 4] = (__bf16)(sc * w1[j]);
                }
                acc0[t] = __builtin_amdgcn_mfma_f32_16x16x32_bf16(af, bW[kl][0], acc0[t], 0, 0, 0);
                acc1[t] = __builtin_amdgcn_mfma_f32_16x16x32_bf16(af, bW[kl][1], acc1[t], 0, 0, 0);
            }
        }

        // ---- partials to LDS: acc (rows q*4..q*4+3 of one col) = one b128
        //      granule at swizzled position -> 2-way max bank aliasing ----
        #pragma unroll
        for (int t = 0; t < 2; ++t) {
            float* rp = red[cur][t] + wave * 512;
            *(floatx4*)(rp + col * 16 + pofs)        = acc0[t];
            *(floatx4*)(rp + (col + 16) * 16 + pofs) = acc1[t];
        }
        // land the prefetched chunk into the other x buffer
        if (it < ITERS - 1)
            *(floatx4*)&xs[cur ^ 1][sword] = pre;
        __syncthreads();

        // ---- reduce: each thread sums 4 waves' granules for one
        //      (tile, col, row-quad): 4x ds_read_b128 + 3 packed adds ----
        {
            const float* rb = red[cur][rt];
            floatx4 s = *(const floatx4*)(rb + rc * 16 + rp4);
            #pragma unroll
            for (int w = 1; w < 4; ++w) {
                floatx4 p = *(const floatx4*)(rb + w * 512 + rc * 16 + rp4);
                s.x += p.x; s.y += p.y; s.z += p.z; s.w += p.w;
            }
            float* op = out + ((size_t)chunk * 32 + rt * 16 + rqd * 4) * 32 + rc;
            op[0]  = s.x;   // rows are 32 floats apart; each row's 32 lanes
            op[32] = s.y;   // write 128B contiguous -> coalesced
            op[64] = s.z;
            op[96] = s.w;
        }
        // next iter writes the other xs/red buffers; the barrier orders reuse
    }
}

extern "C" void kernel_launch(void* const* d_in, const int* in_sizes, int n_in,
                              void* d_out, int out_size, void* d_ws, size_t ws_size,
                              hipStream_t stream) {
    const float* x    = (const float*)d_in[0];
    const float* Wlin = (const float*)d_in[1];
    const float* Wnl  = (const float*)d_in[2];
    float* out        = (float*)d_out;
    nnode_kernel<<<dim3(GRID), dim3(256), 0, stream>>>(x, Wlin, Wnl, out);
}